// Round 11
// baseline (320.670 us; speedup 1.0000x reference)
//
#include <hip/hip_runtime.h>
#include <cstdint>

#define LDP 136          // padded LDS row stride in bf16 elems (272B, 16B-aligned)
#define INFV 3.0e38f
#define CB_STRIDE 147840 // padded diag-major cost elems per batch

typedef short bf16x8 __attribute__((ext_vector_type(8)));
typedef float f32x4  __attribute__((ext_vector_type(4)));

__device__ inline float bf2f(uint32_t bits){
  return __builtin_bit_cast(float, bits << 16);
}
__device__ inline float bf2f_lo(uint32_t w){ return __builtin_bit_cast(float, w << 16); }
__device__ inline float bf2f_hi(uint32_t w){ return __builtin_bit_cast(float, w & 0xffff0000u); }
__device__ inline ushort f2bf(float f){
  uint32_t u = __builtin_bit_cast(uint32_t, f);
  u += 0x7fffu + ((u >> 16) & 1u);   // round-to-nearest-even
  return (ushort)(u >> 16);
}

// ---- DPP helper: VALU cross-lane ------------------------------------------
#define DPPF(x, oldv, ctrl) \
  __builtin_bit_cast(float, __builtin_amdgcn_update_dpp( \
      __builtin_bit_cast(int,(oldv)), __builtin_bit_cast(int,(x)), \
      (ctrl), 0xf, 0xf, false))

__device__ inline float rl(float v, int l){    // readlane (uniform, VALU)
  return __builtin_bit_cast(float, __builtin_amdgcn_readlane(__builtin_bit_cast(int, v), l));
}

// diag-major compact offset of cell (i,j), even-padded per diag so every
// diag's absolute-j byte base is 4B-aligned. Verified R7/R8/R9 (absmax 0).
__device__ inline int diag_off(int i, int j){
  const int d = i + j;
  if (d <= 383){
    return ((d*(d+1))>>1) + ((d+1)>>1) + j;
  } else {
    const int e2 = 767 - d;
    return 147456 - ((e2*(e2+1))>>1) + 193 + ((d-384)>>1) + j - (d-383);
  }
}

// ---------------------------------------------------------------------------
// Kernel 1: cost GEMM (bf16 MFMA) with diag-major epilogue stores.
// (unchanged — refcheck'd R7/R8/R9)
// ---------------------------------------------------------------------------
__global__ __launch_bounds__(256) void dtw_cost_gemm(
    const float* __restrict__ s1, const float* __restrict__ s2,
    ushort* __restrict__ cost)
{
  __shared__ ushort As[128*LDP];
  __shared__ ushort Bs[128*LDP];
  __shared__ float  n1s[128];
  __shared__ float  n2s[128];

  const int b  = blockIdx.y;
  const int ti = blockIdx.x / 3;
  const int tj = blockIdx.x % 3;
  const int t  = threadIdx.x;

  {
    const int row = t >> 1;
    const int par = t & 1;
    const float* Arow = s1 + ((size_t)(b*384 + ti*128 + row)) * 128;
    const float* Brow = s2 + ((size_t)(b*384 + tj*128 + row)) * 128;
    ushort* Asr = As + row*LDP;
    ushort* Bsr = Bs + row*LDP;
#pragma unroll
    for (int q = 0; q < 16; q++){
      const int col = ((2*q + par + 15*row) & 31) * 4;
      float4 va = *(const float4*)(Arow + col);
      float4 vb = *(const float4*)(Brow + col);
      ushort4 ua = make_ushort4(f2bf(va.x), f2bf(va.y), f2bf(va.z), f2bf(va.w));
      ushort4 ub = make_ushort4(f2bf(vb.x), f2bf(vb.y), f2bf(vb.z), f2bf(vb.w));
      *(ushort4*)(Asr + col) = ua;
      *(ushort4*)(Bsr + col) = ub;
    }
  }
  __syncthreads();

  {
    const ushort* rowp = (t < 128) ? (As + t*LDP) : (Bs + (t-128)*LDP);
    float s = 0.0f;
#pragma unroll
    for (int e = 0; e < 128; e += 8){
      bf16x8 v = *(const bf16x8*)(rowp + e);
#pragma unroll
      for (int k = 0; k < 8; k++){
        float f = bf2f((uint16_t)v[k]);
        s += f*f;
      }
    }
    if (t < 128) n1s[t] = s; else n2s[t-128] = s;
  }
  __syncthreads();

  const int lane = t & 63;
  const int wid  = t >> 6;
  const int wr = wid >> 1, wc = wid & 1;
  const int lrow = lane & 15;
  const int lk   = lane >> 4;

  f32x4 acc[4][4] = {};
#pragma unroll
  for (int kk = 0; kk < 4; kk++){
    const int kb = kk*32 + lk*8;
    bf16x8 af[4], bfv[4];
#pragma unroll
    for (int f = 0; f < 4; f++){
      af[f]  = *(const bf16x8*)(As + (wr*64 + f*16 + lrow)*LDP + kb);
      bfv[f] = *(const bf16x8*)(Bs + (wc*64 + f*16 + lrow)*LDP + kb);
    }
#pragma unroll
    for (int i = 0; i < 4; i++)
#pragma unroll
      for (int j = 0; j < 4; j++)
        acc[i][j] = __builtin_amdgcn_mfma_f32_16x16x32_bf16(af[i], bfv[j], acc[i][j], 0, 0, 0);
  }

  ushort* Cb = cost + (size_t)b * CB_STRIDE;
  const int i0 = ti*128 + wr*64;
  const int j0 = tj*128 + wc*64;
  float n2v[4];
#pragma unroll
  for (int fj = 0; fj < 4; fj++) n2v[fj] = n2s[wc*64 + fj*16 + lrow];
#pragma unroll
  for (int fi = 0; fi < 4; fi++){
#pragma unroll
    for (int r = 0; r < 4; r++){
      const int il = wr*64 + fi*16 + lk*4 + r;
      const int i  = i0 + fi*16 + lk*4 + r;
      const float n1v = n1s[il];
#pragma unroll
      for (int fj = 0; fj < 4; fj++){
        float cv = n1v + n2v[fj] - 2.0f*acc[fi][fj][r];
        const int col = j0 + fj*16 + lrow;
        Cb[diag_off(i, col)] = f2bf(cv);
      }
    }
  }
}

// ---------------------------------------------------------------------------
// Kernel 2: DTW DP — anti-diagonal wavefront, TWO batches per wave.
// The two recurrence chains are independent, so each fills the other's
// dependency-stall slots in the lone wave's issue stream (the measured
// ~470 cy/step was stall-dominated, not issue- or memory-bound).
// Staging/addressing identical to the verified R9 kernel, duplicated per
// batch: 2 LDS rings x 3 group-slots x 8 diags, one vmcnt fence per group.
// ---------------------------------------------------------------------------
__global__ __launch_bounds__(64, 1) void dtw_dp(
    const ushort* __restrict__ cost, float* __restrict__ partial)
{
  __shared__ uint32_t lds0[3*8*256];   // batch A ring (24 KiB)
  __shared__ uint32_t lds1[3*8*256];   // batch B ring (24 KiB)
  const int lane = threadIdx.x;
  const int bA = blockIdx.x;
  const int bB = blockIdx.x + 64;
  const ushort* CpA = cost + (size_t)bA * CB_STRIDE;
  const ushort* CpB = cost + (size_t)bB * CB_STRIDE;

  typedef __attribute__((address_space(1))) const uint32_t GU32;
  typedef __attribute__((address_space(3))) uint32_t LU32;

  // ---- seeds first (plain loads complete before any DMA is issued) ----
  float Aa0 = (lane == 0) ? bf2f((uint32_t)CpA[0]) : INFV;
  float Ba0 = (lane == 0) ? bf2f((uint32_t)CpB[0]) : INFV;
  float Aa1=INFV,Aa2=INFV,Aa3=INFV,Aa4=INFV,Aa5=INFV;
  float Ab0=INFV,Ab1=INFV,Ab2=INFV,Ab3=INFV,Ab4=INFV,Ab5=INFV;
  float Ba1=INFV,Ba2=INFV,Ba3=INFV,Ba4=INFV,Ba5=INFV;
  float Bb0=INFV,Bb1=INFV,Bb2=INFV,Bb3=INFV,Bb4=INFV,Bb5=INFV;
  float Asa=INFV, Asb=INFV, Bsa=INFV, Bsb=INFV;

  int pds = 1, bbs = 4;   // stage-side diag / byte base (verified R9)
  int pdc = 1, bbc = 4;   // consume-side

#define ADVX(pd, bb) do{ \
    int adv_ = ((pd) < 383) ? ((pd) + 1 + (((pd) & 1) ^ 1)) \
             : (((pd) == 383) ? 384 : ((767 - (pd)) + ((pd) & 1) - 1)); \
    (bb) += 2*adv_; (pd)++; \
  } while(0)

  // stage one diag for BOTH batches (2 DMAs), 16B/lane window
#define SSTEP2(SLOTB) do{ \
    int gb_ = bbs < 294656 ? bbs : 294656; gb_ &= ~15; \
    const char* gpA_ = (const char*)CpA + gb_ + 16*lane; \
    const char* gpB_ = (const char*)CpB + gb_ + 16*lane; \
    __builtin_amdgcn_global_load_lds((GU32*)gpA_, (LU32*)&lds0[SLOTB], 16, 0, 0); \
    __builtin_amdgcn_global_load_lds((GU32*)gpB_, (LU32*)&lds1[SLOTB], 16, 0, 0); \
    ADVX(pds, bbs); \
  } while(0)

#define WAITV(n) do { \
    asm volatile("s_waitcnt vmcnt(" #n ")" ::: "memory"); \
    __builtin_amdgcn_sched_barrier(0); \
  } while(0)

  // recurrence body (verified R7-R9)
#define BODYP(W0,W1,W2, p0,p1,p2,p3,p4,p5, q0,q1,q2,q3,q4,q5, shp, shq) do{ \
    float c0=bf2f_lo(W0), c1=bf2f_hi(W0), c2=bf2f_lo(W1), \
          c3=bf2f_hi(W1), c4=bf2f_lo(W2), c5=bf2f_hi(W2); \
    float n0 = c0 + fminf(fminf(p0, shp), shq); \
    float n1 = c1 + fminf(fminf(p1, p0), q0); \
    float n2 = c2 + fminf(fminf(p2, p1), q1); \
    float n3 = c3 + fminf(fminf(p3, p2), q2); \
    float n4 = c4 + fminf(fminf(p4, p3), q3); \
    float n5 = c5 + fminf(fminf(p5, p4), q4); \
    float sh_ = DPPF(n5, INFV, 0x111); \
    sh_ = (lane==16) ? rl(n5,15) : sh_; \
    sh_ = (lane==32) ? rl(n5,31) : sh_; \
    sh_ = (lane==48) ? rl(n5,47) : sh_; \
    q0=n0; q1=n1; q2=n2; q3=n3; q4=n4; q5=n5; \
    shq = sh_; \
  } while(0)

  // one diag step for BOTH batches; _AB: p=a-set, writes b-set (odd diags)
#define CSTEP2_AB(SLOTB) do{ \
    int gb_ = bbc < 294656 ? bbc : 294656; gb_ &= ~15; \
    int ix_ = (SLOTB) + ((bbc - gb_) >> 2) + 3*lane; \
    uint32_t AW0=lds0[ix_], AW1=lds0[ix_+1], AW2=lds0[ix_+2]; \
    uint32_t BW0=lds1[ix_], BW1=lds1[ix_+1], BW2=lds1[ix_+2]; \
    ADVX(pdc, bbc); \
    BODYP(AW0,AW1,AW2, Aa0,Aa1,Aa2,Aa3,Aa4,Aa5, Ab0,Ab1,Ab2,Ab3,Ab4,Ab5, Asa, Asb); \
    BODYP(BW0,BW1,BW2, Ba0,Ba1,Ba2,Ba3,Ba4,Ba5, Bb0,Bb1,Bb2,Bb3,Bb4,Bb5, Bsa, Bsb); \
  } while(0)
#define CSTEP2_BA(SLOTB) do{ \
    int gb_ = bbc < 294656 ? bbc : 294656; gb_ &= ~15; \
    int ix_ = (SLOTB) + ((bbc - gb_) >> 2) + 3*lane; \
    uint32_t AW0=lds0[ix_], AW1=lds0[ix_+1], AW2=lds0[ix_+2]; \
    uint32_t BW0=lds1[ix_], BW1=lds1[ix_+1], BW2=lds1[ix_+2]; \
    ADVX(pdc, bbc); \
    BODYP(AW0,AW1,AW2, Ab0,Ab1,Ab2,Ab3,Ab4,Ab5, Aa0,Aa1,Aa2,Aa3,Aa4,Aa5, Asb, Asa); \
    BODYP(BW0,BW1,BW2, Bb0,Bb1,Bb2,Bb3,Bb4,Bb5, Ba0,Ba1,Ba2,Ba3,Ba4,Ba5, Bsb, Bsa); \
  } while(0)

  // ---- prologue: stage groups 0 (slot 0) and 1 (slot 1): 32 DMAs ----
  for (int s = 0; s < 2; ++s)
    for (int t = 0; t < 8; ++t)
      SSTEP2((s*8 + t)*256);

  // ---- main: groups 0..94 consume diags 1..760; stage g+2 (<=95) ----
  int cs = 0, ss = 2;
  for (int g = 0; g < 95; ++g){
    WAITV(16);
    const int gb = cs * 2048;
    CSTEP2_AB(gb+   0); CSTEP2_BA(gb+ 256);
    CSTEP2_AB(gb+ 512); CSTEP2_BA(gb+ 768);
    CSTEP2_AB(gb+1024); CSTEP2_BA(gb+1280);
    CSTEP2_AB(gb+1536); CSTEP2_BA(gb+1792);
    if (g < 94){
      const int sbb = ss * 2048;
      SSTEP2(sbb+   0); SSTEP2(sbb+ 256);
      SSTEP2(sbb+ 512); SSTEP2(sbb+ 768);
      SSTEP2(sbb+1024); SSTEP2(sbb+1280);
      SSTEP2(sbb+1536); SSTEP2(sbb+1792);
    }
    cs = (cs == 2) ? 0 : cs + 1;
    ss = (ss == 2) ? 0 : ss + 1;
  }

  // ---- tail: group 95 = diags 761..766 (6 steps; last is _BA -> a-sets) ----
  WAITV(0);
  {
    const int gb = cs * 2048;
    CSTEP2_AB(gb+   0); CSTEP2_BA(gb+ 256);
    CSTEP2_AB(gb+ 512); CSTEP2_BA(gb+ 768);
    CSTEP2_AB(gb+1024); CSTEP2_BA(gb+1280);
  }

  if (lane == 63){
    partial[bA] = Aa5;   // D[383][383] of batch A
    partial[bB] = Ba5;   // D[383][383] of batch B
  }

#undef CSTEP2_AB
#undef CSTEP2_BA
#undef BODYP
#undef WAITV
#undef SSTEP2
#undef ADVX
}

// ---------------------------------------------------------------------------
// Kernel 3: mean of 128 partials -> out[0]
// ---------------------------------------------------------------------------
__global__ __launch_bounds__(64) void dtw_reduce(
    const float* __restrict__ partial, float* __restrict__ out)
{
  const int l = threadIdx.x;
  float v = partial[l] + partial[l + 64];
#pragma unroll
  for (int d = 32; d >= 1; d >>= 1) v += __shfl_xor(v, d, 64);
  if (l == 0) out[0] = v * (1.0f/128.0f);
}

extern "C" void kernel_launch(void* const* d_in, const int* in_sizes, int n_in,
                              void* d_out, int out_size, void* d_ws, size_t ws_size,
                              hipStream_t stream)
{
  (void)in_sizes; (void)n_in; (void)out_size; (void)ws_size;
  const float* s1 = (const float*)d_in[0];
  const float* s2 = (const float*)d_in[1];
  float* out = (float*)d_out;

  ushort* cost    = (ushort*)d_ws;                                     // 128*147840*2 B
  float*  partial = (float*)((char*)d_ws + (size_t)128*CB_STRIDE*2);   // 128 floats

  dtw_cost_gemm<<<dim3(9, 128), dim3(256), 0, stream>>>(s1, s2, cost);
  dtw_dp<<<dim3(64), dim3(64), 0, stream>>>(cost, partial);
  dtw_reduce<<<dim3(1), dim3(64), 0, stream>>>(partial, out);
}

// Round 12
// 217.984 us; speedup vs baseline: 1.4711x; 1.4711x over previous
//
#include <hip/hip_runtime.h>
#include <cstdint>

#define LDP 136          // padded LDS row stride in bf16 elems (272B, 16B-aligned)
#define INFV 3.0e38f
#define CB_STRIDE 147840 // padded diag-major cost elems per batch

typedef short bf16x8 __attribute__((ext_vector_type(8)));
typedef float f32x4  __attribute__((ext_vector_type(4)));

__device__ inline float bf2f(uint32_t bits){
  return __builtin_bit_cast(float, bits << 16);
}
__device__ inline float bf2f_lo(uint32_t w){ return __builtin_bit_cast(float, w << 16); }
__device__ inline float bf2f_hi(uint32_t w){ return __builtin_bit_cast(float, w & 0xffff0000u); }
__device__ inline ushort f2bf(float f){
  uint32_t u = __builtin_bit_cast(uint32_t, f);
  u += 0x7fffu + ((u >> 16) & 1u);   // round-to-nearest-even
  return (ushort)(u >> 16);
}

// ---- DPP helper: VALU cross-lane ------------------------------------------
#define DPPF(x, oldv, ctrl) \
  __builtin_bit_cast(float, __builtin_amdgcn_update_dpp( \
      __builtin_bit_cast(int,(oldv)), __builtin_bit_cast(int,(x)), \
      (ctrl), 0xf, 0xf, false))

__device__ inline float rl(float v, int l){    // readlane (uniform, VALU)
  return __builtin_bit_cast(float, __builtin_amdgcn_readlane(__builtin_bit_cast(int, v), l));
}

// diag-major compact offset of cell (i,j), even-padded per diag so every
// diag's absolute-j byte base is 4B-aligned. Verified R7-R10 (absmax 0).
__device__ inline int diag_off(int i, int j){
  const int d = i + j;
  if (d <= 383){
    return ((d*(d+1))>>1) + ((d+1)>>1) + j;
  } else {
    const int e2 = 767 - d;
    return 147456 - ((e2*(e2+1))>>1) + 193 + ((d-384)>>1) + j - (d-383);
  }
}

// ---------------------------------------------------------------------------
// Kernel 1: cost GEMM (bf16 MFMA) with diag-major epilogue stores.
// (unchanged — refcheck'd R7-R10)
// ---------------------------------------------------------------------------
__global__ __launch_bounds__(256) void dtw_cost_gemm(
    const float* __restrict__ s1, const float* __restrict__ s2,
    ushort* __restrict__ cost)
{
  __shared__ ushort As[128*LDP];
  __shared__ ushort Bs[128*LDP];
  __shared__ float  n1s[128];
  __shared__ float  n2s[128];

  const int b  = blockIdx.y;
  const int ti = blockIdx.x / 3;
  const int tj = blockIdx.x % 3;
  const int t  = threadIdx.x;

  {
    const int row = t >> 1;
    const int par = t & 1;
    const float* Arow = s1 + ((size_t)(b*384 + ti*128 + row)) * 128;
    const float* Brow = s2 + ((size_t)(b*384 + tj*128 + row)) * 128;
    ushort* Asr = As + row*LDP;
    ushort* Bsr = Bs + row*LDP;
#pragma unroll
    for (int q = 0; q < 16; q++){
      const int col = ((2*q + par + 15*row) & 31) * 4;
      float4 va = *(const float4*)(Arow + col);
      float4 vb = *(const float4*)(Brow + col);
      ushort4 ua = make_ushort4(f2bf(va.x), f2bf(va.y), f2bf(va.z), f2bf(va.w));
      ushort4 ub = make_ushort4(f2bf(vb.x), f2bf(vb.y), f2bf(vb.z), f2bf(vb.w));
      *(ushort4*)(Asr + col) = ua;
      *(ushort4*)(Bsr + col) = ub;
    }
  }
  __syncthreads();

  {
    const ushort* rowp = (t < 128) ? (As + t*LDP) : (Bs + (t-128)*LDP);
    float s = 0.0f;
#pragma unroll
    for (int e = 0; e < 128; e += 8){
      bf16x8 v = *(const bf16x8*)(rowp + e);
#pragma unroll
      for (int k = 0; k < 8; k++){
        float f = bf2f((uint16_t)v[k]);
        s += f*f;
      }
    }
    if (t < 128) n1s[t] = s; else n2s[t-128] = s;
  }
  __syncthreads();

  const int lane = t & 63;
  const int wid  = t >> 6;
  const int wr = wid >> 1, wc = wid & 1;
  const int lrow = lane & 15;
  const int lk   = lane >> 4;

  f32x4 acc[4][4] = {};
#pragma unroll
  for (int kk = 0; kk < 4; kk++){
    const int kb = kk*32 + lk*8;
    bf16x8 af[4], bfv[4];
#pragma unroll
    for (int f = 0; f < 4; f++){
      af[f]  = *(const bf16x8*)(As + (wr*64 + f*16 + lrow)*LDP + kb);
      bfv[f] = *(const bf16x8*)(Bs + (wc*64 + f*16 + lrow)*LDP + kb);
    }
#pragma unroll
    for (int i = 0; i < 4; i++)
#pragma unroll
      for (int j = 0; j < 4; j++)
        acc[i][j] = __builtin_amdgcn_mfma_f32_16x16x32_bf16(af[i], bfv[j], acc[i][j], 0, 0, 0);
  }

  ushort* Cb = cost + (size_t)b * CB_STRIDE;
  const int i0 = ti*128 + wr*64;
  const int j0 = tj*128 + wc*64;
  float n2v[4];
#pragma unroll
  for (int fj = 0; fj < 4; fj++) n2v[fj] = n2s[wc*64 + fj*16 + lrow];
#pragma unroll
  for (int fi = 0; fi < 4; fi++){
#pragma unroll
    for (int r = 0; r < 4; r++){
      const int il = wr*64 + fi*16 + lk*4 + r;
      const int i  = i0 + fi*16 + lk*4 + r;
      const float n1v = n1s[il];
#pragma unroll
      for (int fj = 0; fj < 4; fj++){
        float cv = n1v + n2v[fj] - 2.0f*acc[fi][fj][r];
        const int col = j0 + fj*16 + lrow;
        Cb[diag_off(i, col)] = f2bf(cv);
      }
    }
  }
}

// ---------------------------------------------------------------------------
// Kernel 2: DTW DP — anti-diagonal wavefront over diag-major cost.
// R9 staging (4 slots x 8 diags, one vmcnt fence per group) + BATCHED LDS
// reads: all 8 read-indices computed upfront, all 24 ds_reads issued
// back-to-back into registers, THEN 8 pure-VALU steps. One LDS-latency
// exposure per group instead of per step.
// ---------------------------------------------------------------------------
__global__ __launch_bounds__(64, 1) void dtw_dp(
    const ushort* __restrict__ cost, float* __restrict__ partial)
{
  __shared__ uint32_t lds[4*8*256];   // 4 group-slots x 8 diags x 256 dwords
  const int b    = blockIdx.x;
  const int lane = threadIdx.x;
  const ushort* Cp = cost + (size_t)b * CB_STRIDE;

  typedef __attribute__((address_space(1))) const uint32_t GU32;
  typedef __attribute__((address_space(3))) uint32_t LU32;

  // ---- seed first (plain load completes before any DMA is issued) ----
  float a0 = (lane == 0) ? bf2f((uint32_t)Cp[0]) : INFV;   // D(0)
  float a1=INFV,a2=INFV,a3=INFV,a4=INFV,a5=INFV;
  float b0=INFV,b1=INFV,b2=INFV,b3=INFV,b4=INFV,b5=INFV;   // D(-1)
  float sa=INFV, sb=INFV;

  int pds = 1, bbs = 4;   // stage-side diag / byte base (verified R9)
  int pdc = 1, bbc = 4;   // consume-side

#define ADVX(pd, bb) do{ \
    int adv_ = ((pd) < 383) ? ((pd) + 1 + (((pd) & 1) ^ 1)) \
             : (((pd) == 383) ? 384 : ((767 - (pd)) + ((pd) & 1) - 1)); \
    (bb) += 2*adv_; (pd)++; \
  } while(0)

#define SSTEP(SLOTB) do{ \
    int gb_ = bbs < 294656 ? bbs : 294656; gb_ &= ~15; \
    const char* gp_ = (const char*)Cp + gb_ + 16*lane; \
    __builtin_amdgcn_global_load_lds((GU32*)gp_, (LU32*)&lds[SLOTB], 16, 0, 0); \
    ADVX(pds, bbs); \
  } while(0)

#define WAITV(n) do { \
    asm volatile("s_waitcnt vmcnt(" #n ")" ::: "memory"); \
    __builtin_amdgcn_sched_barrier(0); \
  } while(0)

  // recurrence body (verified R7-R10)
#define BODYP(W0,W1,W2, p0,p1,p2,p3,p4,p5, q0,q1,q2,q3,q4,q5, shp, shq) do{ \
    float c0=bf2f_lo(W0), c1=bf2f_hi(W0), c2=bf2f_lo(W1), \
          c3=bf2f_hi(W1), c4=bf2f_lo(W2), c5=bf2f_hi(W2); \
    float n0 = c0 + fminf(fminf(p0, shp), shq); \
    float n1 = c1 + fminf(fminf(p1, p0), q0); \
    float n2 = c2 + fminf(fminf(p2, p1), q1); \
    float n3 = c3 + fminf(fminf(p3, p2), q2); \
    float n4 = c4 + fminf(fminf(p4, p3), q3); \
    float n5 = c5 + fminf(fminf(p5, p4), q4); \
    float sh_ = DPPF(n5, INFV, 0x111); \
    sh_ = (lane==16) ? rl(n5,15) : sh_; \
    sh_ = (lane==32) ? rl(n5,31) : sh_; \
    sh_ = (lane==48) ? rl(n5,47) : sh_; \
    q0=n0; q1=n1; q2=n2; q3=n3; q4=n4; q5=n5; \
    shq = sh_; \
  } while(0)

#define BODY_AB(W0,W1,W2) BODYP(W0,W1,W2, a0,a1,a2,a3,a4,a5, b0,b1,b2,b3,b4,b5, sa, sb)
#define BODY_BA(W0,W1,W2) BODYP(W0,W1,W2, b0,b1,b2,b3,b4,b5, a0,a1,a2,a3,a4,a5, sb, sa)

#define GIDX(IX, SL) do{ \
    int gb_ = bbc < 294656 ? bbc : 294656; gb_ &= ~15; \
    IX = (SL) + ((bbc - gb_) >> 2) + 3*lane; \
    ADVX(pdc, bbc); \
  } while(0)

  // one group: indices upfront, 24 batched ds_reads, 8 pure-VALU steps
#define GROUP8(GB) do{ \
    int x0,x1,x2,x3,x4,x5,x6,x7; \
    GIDX(x0,(GB)+0);    GIDX(x1,(GB)+256); \
    GIDX(x2,(GB)+512);  GIDX(x3,(GB)+768); \
    GIDX(x4,(GB)+1024); GIDX(x5,(GB)+1280); \
    GIDX(x6,(GB)+1536); GIDX(x7,(GB)+1792); \
    uint32_t w00=lds[x0],w01=lds[x0+1],w02=lds[x0+2]; \
    uint32_t w10=lds[x1],w11=lds[x1+1],w12=lds[x1+2]; \
    uint32_t w20=lds[x2],w21=lds[x2+1],w22=lds[x2+2]; \
    uint32_t w30=lds[x3],w31=lds[x3+1],w32=lds[x3+2]; \
    uint32_t w40=lds[x4],w41=lds[x4+1],w42=lds[x4+2]; \
    uint32_t w50=lds[x5],w51=lds[x5+1],w52=lds[x5+2]; \
    uint32_t w60=lds[x6],w61=lds[x6+1],w62=lds[x6+2]; \
    uint32_t w70=lds[x7],w71=lds[x7+1],w72=lds[x7+2]; \
    BODY_AB(w00,w01,w02); BODY_BA(w10,w11,w12); \
    BODY_AB(w20,w21,w22); BODY_BA(w30,w31,w32); \
    BODY_AB(w40,w41,w42); BODY_BA(w50,w51,w52); \
    BODY_AB(w60,w61,w62); BODY_BA(w70,w71,w72); \
  } while(0)

  // ---- prologue: stage groups 0..2 (diags 1..24) into slots 0..2 ----
  for (int s = 0; s < 3; ++s)
    for (int t = 0; t < 8; ++t)
      SSTEP((s*8 + t)*256);

  // ---- main: groups 0..93 consume diags 1..752; stage g+3 (<=95) ----
  for (int g = 0; g < 94; ++g){
    WAITV(16);
    GROUP8((g & 3) * 2048);
    if (g < 93){
      const int sbb = ((g+3) & 3) * 2048;
      SSTEP(sbb+   0); SSTEP(sbb+ 256);
      SSTEP(sbb+ 512); SSTEP(sbb+ 768);
      SSTEP(sbb+1024); SSTEP(sbb+1280);
      SSTEP(sbb+1536); SSTEP(sbb+1792);
    }
  }

  // ---- group 94: diags 753..760 (slot 2) ----
  WAITV(8);
  GROUP8(2*2048);

  // ---- group 95: diags 761..766 (slot 3, 6 steps) ----
  WAITV(0);
  {
    const int GB = 3*2048;
    int x0,x1,x2,x3,x4,x5;
    GIDX(x0,GB+0);    GIDX(x1,GB+256);
    GIDX(x2,GB+512);  GIDX(x3,GB+768);
    GIDX(x4,GB+1024); GIDX(x5,GB+1280);
    uint32_t w00=lds[x0],w01=lds[x0+1],w02=lds[x0+2];
    uint32_t w10=lds[x1],w11=lds[x1+1],w12=lds[x1+2];
    uint32_t w20=lds[x2],w21=lds[x2+1],w22=lds[x2+2];
    uint32_t w30=lds[x3],w31=lds[x3+1],w32=lds[x3+2];
    uint32_t w40=lds[x4],w41=lds[x4+1],w42=lds[x4+2];
    uint32_t w50=lds[x5],w51=lds[x5+1],w52=lds[x5+2];
    BODY_AB(w00,w01,w02); BODY_BA(w10,w11,w12);
    BODY_AB(w20,w21,w22); BODY_BA(w30,w31,w32);
    BODY_AB(w40,w41,w42); BODY_BA(w50,w51,w52);
  }

  if (lane == 63) partial[b] = a5;   // D[383][383] (diag 766 even -> a-set)

#undef GROUP8
#undef GIDX
#undef BODY_AB
#undef BODY_BA
#undef BODYP
#undef WAITV
#undef SSTEP
#undef ADVX
}

// ---------------------------------------------------------------------------
// Kernel 3: mean of 128 partials -> out[0]
// ---------------------------------------------------------------------------
__global__ __launch_bounds__(64) void dtw_reduce(
    const float* __restrict__ partial, float* __restrict__ out)
{
  const int l = threadIdx.x;
  float v = partial[l] + partial[l + 64];
#pragma unroll
  for (int d = 32; d >= 1; d >>= 1) v += __shfl_xor(v, d, 64);
  if (l == 0) out[0] = v * (1.0f/128.0f);
}

extern "C" void kernel_launch(void* const* d_in, const int* in_sizes, int n_in,
                              void* d_out, int out_size, void* d_ws, size_t ws_size,
                              hipStream_t stream)
{
  (void)in_sizes; (void)n_in; (void)out_size; (void)ws_size;
  const float* s1 = (const float*)d_in[0];
  const float* s2 = (const float*)d_in[1];
  float* out = (float*)d_out;

  ushort* cost    = (ushort*)d_ws;                                     // 128*147840*2 B
  float*  partial = (float*)((char*)d_ws + (size_t)128*CB_STRIDE*2);   // 128 floats

  dtw_cost_gemm<<<dim3(9, 128), dim3(256), 0, stream>>>(s1, s2, cost);
  dtw_dp<<<dim3(128), dim3(64), 0, stream>>>(cost, partial);
  dtw_reduce<<<dim3(1), dim3(64), 0, stream>>>(partial, out);
}

// Round 13
// 200.617 us; speedup vs baseline: 1.5984x; 1.0866x over previous
//
#include <hip/hip_runtime.h>
#include <cstdint>

#define LDP 136          // padded LDS row stride in bf16 elems (272B, 16B-aligned)
#define INFV 3.0e38f

typedef short bf16x8 __attribute__((ext_vector_type(8)));
typedef float f32x4  __attribute__((ext_vector_type(4)));

__device__ inline float bf2f(uint32_t bits){
  return __builtin_bit_cast(float, bits << 16);
}
__device__ inline float bf2f_lo(uint32_t w){ return __builtin_bit_cast(float, w << 16); }
__device__ inline float bf2f_hi(uint32_t w){ return __builtin_bit_cast(float, w & 0xffff0000u); }
__device__ inline ushort f2bf(float f){
  uint32_t u = __builtin_bit_cast(uint32_t, f);
  u += 0x7fffu + ((u >> 16) & 1u);   // round-to-nearest-even
  return (ushort)(u >> 16);
}

// ---- DPP helpers: VALU cross-lane ----------------------------------------
#define DPPF(x, oldv, ctrl) \
  __builtin_bit_cast(float, __builtin_amdgcn_update_dpp( \
      __builtin_bit_cast(int,(oldv)), __builtin_bit_cast(int,(x)), \
      (ctrl), 0xf, 0xf, false))

__device__ inline float scan_add16(float x){   // inclusive add-scan within 16-lane row
  x += DPPF(x, 0.0f, 0x111);
  x += DPPF(x, 0.0f, 0x112);
  x += DPPF(x, 0.0f, 0x114);
  x += DPPF(x, 0.0f, 0x118);
  return x;
}
__device__ inline float scan_min16(float x){   // inclusive min-scan within 16-lane row
  x = fminf(x, DPPF(x, INFV, 0x111));
  x = fminf(x, DPPF(x, INFV, 0x112));
  x = fminf(x, DPPF(x, INFV, 0x114));
  x = fminf(x, DPPF(x, INFV, 0x118));
  return x;
}
__device__ inline float rl(float v, int l){    // readlane (uniform, VALU)
  return __builtin_bit_cast(float, __builtin_amdgcn_readlane(__builtin_bit_cast(int, v), l));
}

// ---------------------------------------------------------------------------
// Kernel 1: cost[b][i][j] = ||s1[b,i]||^2 + ||s2[b,j]||^2 - 2*dot  (bf16 out)
// Row-major output (R5-verified version).
// ---------------------------------------------------------------------------
__global__ __launch_bounds__(256) void dtw_cost_gemm(
    const float* __restrict__ s1, const float* __restrict__ s2,
    ushort* __restrict__ cost)
{
  __shared__ ushort As[128*LDP];
  __shared__ ushort Bs[128*LDP];
  __shared__ float  n1s[128];
  __shared__ float  n2s[128];

  const int b  = blockIdx.y;
  const int ti = blockIdx.x / 3;
  const int tj = blockIdx.x % 3;
  const int t  = threadIdx.x;

  {
    const int row = t >> 1;
    const int par = t & 1;
    const float* Arow = s1 + ((size_t)(b*384 + ti*128 + row)) * 128;
    const float* Brow = s2 + ((size_t)(b*384 + tj*128 + row)) * 128;
    ushort* Asr = As + row*LDP;
    ushort* Bsr = Bs + row*LDP;
#pragma unroll
    for (int q = 0; q < 16; q++){
      const int col = ((2*q + par + 15*row) & 31) * 4;
      float4 va = *(const float4*)(Arow + col);
      float4 vb = *(const float4*)(Brow + col);
      ushort4 ua = make_ushort4(f2bf(va.x), f2bf(va.y), f2bf(va.z), f2bf(va.w));
      ushort4 ub = make_ushort4(f2bf(vb.x), f2bf(vb.y), f2bf(vb.z), f2bf(vb.w));
      *(ushort4*)(Asr + col) = ua;
      *(ushort4*)(Bsr + col) = ub;
    }
  }
  __syncthreads();

  {
    const ushort* rowp = (t < 128) ? (As + t*LDP) : (Bs + (t-128)*LDP);
    float s = 0.0f;
#pragma unroll
    for (int e = 0; e < 128; e += 8){
      bf16x8 v = *(const bf16x8*)(rowp + e);
#pragma unroll
      for (int k = 0; k < 8; k++){
        float f = bf2f((uint16_t)v[k]);
        s += f*f;
      }
    }
    if (t < 128) n1s[t] = s; else n2s[t-128] = s;
  }
  __syncthreads();

  const int lane = t & 63;
  const int wid  = t >> 6;
  const int wr = wid >> 1, wc = wid & 1;
  const int lrow = lane & 15;
  const int lk   = lane >> 4;

  f32x4 acc[4][4] = {};
#pragma unroll
  for (int kk = 0; kk < 4; kk++){
    const int kb = kk*32 + lk*8;
    bf16x8 af[4], bfv[4];
#pragma unroll
    for (int f = 0; f < 4; f++){
      af[f]  = *(const bf16x8*)(As + (wr*64 + f*16 + lrow)*LDP + kb);
      bfv[f] = *(const bf16x8*)(Bs + (wc*64 + f*16 + lrow)*LDP + kb);
    }
#pragma unroll
    for (int i = 0; i < 4; i++)
#pragma unroll
      for (int j = 0; j < 4; j++)
        acc[i][j] = __builtin_amdgcn_mfma_f32_16x16x32_bf16(af[i], bfv[j], acc[i][j], 0, 0, 0);
  }

  ushort* Cb = cost + (size_t)b * 147456;  // 384*384
  const int i0 = ti*128 + wr*64;
  const int j0 = tj*128 + wc*64;
  float n2v[4];
#pragma unroll
  for (int fj = 0; fj < 4; fj++) n2v[fj] = n2s[wc*64 + fj*16 + lrow];
#pragma unroll
  for (int fi = 0; fi < 4; fi++){
#pragma unroll
    for (int r = 0; r < 4; r++){
      const int il = wr*64 + fi*16 + lk*4 + r;
      const int i  = i0 + fi*16 + lk*4 + r;
      const float n1v = n1s[il];
#pragma unroll
      for (int fj = 0; fj < 4; fj++){
        float cv = n1v + n2v[fj] - 2.0f*acc[fi][fj][r];
        Cb[(size_t)i*384 + (j0 + fj*16 + lrow)] = f2bf(cv);
      }
    }
  }
}

// ---------------------------------------------------------------------------
// Kernel 2: DTW DP — R4/R5-verified row-scan (Stage A/B software pipeline),
// now packed 8 WAVES PER BLOCK (one batch per wave): 2 co-resident waves per
// SIMD so the hardware fills one wave's load/hazard stalls with the other's
// ready instructions. Waves are fully independent (no LDS, no barriers).
// ---------------------------------------------------------------------------
__global__ __launch_bounds__(512, 2) void dtw_dp(
    const ushort* __restrict__ cost, float* __restrict__ partial)
{
  const int lane = threadIdx.x & 63;
  const int b    = blockIdx.x * 8 + (threadIdx.x >> 6);   // batch per wave
  const int row  = lane >> 4;           // 16-lane DPP row id (0..3)
  const uint32_t* Cw = (const uint32_t*)(cost + (size_t)b * 147456);
  const int wb = lane * 3;   // 3 dwords = 6 bf16 per lane per row (row = 192 dwords)

  float r0,r1,r2,r3,r4,r5;                       // DP state (prev row)
  float sp0,sp1,sp2,sp3,sp4,sp5;                 // S[j] for pending row
  float dq0,dq1,dq2,dq3,dq4,dq5;                 // c[j]-S[j] for pending row
  uint32_t ring[4][3];

#define LOADROW(sl, ri) do { \
    int rr_ = (ri); rr_ = rr_ > 383 ? 383 : rr_; \
    const uint32_t* p_ = Cw + (size_t)rr_*192 + wb; \
    ring[sl][0]=p_[0]; ring[sl][1]=p_[1]; ring[sl][2]=p_[2]; \
  } while(0)

  // Stage A: S (global inclusive prefix sum of row costs) and D = c - S.
#define STAGE_A(W0,W1,W2, S0,S1,S2,S3,S4,S5, D0,D1,D2,D3,D4,D5) do { \
    float c0=bf2f_lo(W0), c1=bf2f_hi(W0), c2=bf2f_lo(W1), \
          c3=bf2f_hi(W1), c4=bf2f_lo(W2), c5=bf2f_hi(W2); \
    float t0_=c0, t1_=t0_+c1, t2_=t1_+c2, t3_=t2_+c3, t4_=t3_+c4, t5_=t4_+c5; \
    float incl = scan_add16(t5_); \
    float exl  = DPPF(incl, 0.0f, 0x111); \
    float ta=rl(incl,15), tb=rl(incl,31), tc=rl(incl,47); \
    float g1 = (row>=1)? ta : 0.0f; \
    float g2 = (row>=2)? tb : 0.0f; \
    float g3 = (row>=3)? tc : 0.0f; \
    float excl = exl + ((g1+g2)+g3); \
    S0=t0_+excl; S1=t1_+excl; S2=t2_+excl; S3=t3_+excl; S4=t4_+excl; S5=t5_+excl; \
    D0=c0-S0; D1=c1-S1; D2=c2-S2; D3=c3-S3; D4=c4-S4; D5=c5-S5; \
  } while(0)

  // Stage B: x_j = D_j + min(r_j, r_{j-1}); prefix-min (Sklansky d=3);
  // 16-scan + boundary min; r_j = min(p_j, e) + S_j.
#define STAGE_B(S0,S1,S2,S3,S4,S5, D0,D1,D2,D3,D4,D5) do { \
    float yv = DPPF(r5, INFV, 0x111); \
    float q0=rl(r5,15), q1=rl(r5,31), q2=rl(r5,47); \
    float f1 = (lane==16)? q0 : INFV; \
    float f2 = (lane==32)? q1 : INFV; \
    float f3 = (lane==48)? q2 : INFV; \
    float pm0 = fminf(fminf(f1,f2), fminf(f3,yv)); \
    float x0 = D0 + fminf(r0, pm0); \
    float x1 = D1 + fminf(r1, r0); \
    float x2 = D2 + fminf(r2, r1); \
    float x3 = D3 + fminf(r3, r2); \
    float x4 = D4 + fminf(r4, r3); \
    float x5 = D5 + fminf(r5, r4); \
    float y1 = fminf(x0,x1), y3 = fminf(x2,x3), y5 = fminf(x4,x5); \
    float p2 = fminf(y1,x2), p3 = fminf(y1,y3); \
    float p4 = fminf(p3,x4), p5 = fminf(p3,y5); \
    float im = scan_min16(p5); \
    float ym = DPPF(im, INFV, 0x111); \
    float u0=rl(im,15), u1=rl(im,31), u2=rl(im,47); \
    float h1=(row>=1)?u0:INFV, h2=(row>=2)?u1:INFV, h3=(row>=3)?u2:INFV; \
    float e = fminf(fminf(h1,h2), fminf(h3,ym)); \
    r0 = fminf(x0,e)+S0; \
    r1 = fminf(y1,e)+S1; \
    r2 = fminf(p2,e)+S2; \
    r3 = fminf(p3,e)+S3; \
    r4 = fminf(p4,e)+S4; \
    r5 = fminf(p5,e)+S5; \
  } while(0)

  // body(i): read row i+1 from slot, start load of row i+5 into same slot,
  // Stage A(i+1) into fresh regs, Stage B(i) on pending regs, rotate.
#define BODY(i, sl) do { \
    uint32_t a0=ring[sl][0], a1=ring[sl][1], a2=ring[sl][2]; \
    LOADROW(sl, (i)+5); \
    float sn0,sn1,sn2,sn3,sn4,sn5, dn0,dn1,dn2,dn3,dn4,dn5; \
    STAGE_A(a0,a1,a2, sn0,sn1,sn2,sn3,sn4,sn5, dn0,dn1,dn2,dn3,dn4,dn5); \
    STAGE_B(sp0,sp1,sp2,sp3,sp4,sp5, dq0,dq1,dq2,dq3,dq4,dq5); \
    sp0=sn0; sp1=sn1; sp2=sn2; sp3=sn3; sp4=sn4; sp5=sn5; \
    dq0=dn0; dq1=dn1; dq2=dn2; dq3=dn3; dq4=dn4; dq5=dn5; \
  } while(0)

  // ---- prologue: rows 0..3 in ring; row0 -> r; row1 -> sp/dq ----
  LOADROW(0,0); LOADROW(1,1); LOADROW(2,2); LOADROW(3,3);
  {
    uint32_t a0=ring[0][0], a1=ring[0][1], a2=ring[0][2];
    STAGE_A(a0,a1,a2, sp0,sp1,sp2,sp3,sp4,sp5, dq0,dq1,dq2,dq3,dq4,dq5);
    r0=sp0; r1=sp1; r2=sp2; r3=sp3; r4=sp4; r5=sp5;   // DTW row 0 = prefix sums
  }
  {
    uint32_t a0=ring[1][0], a1=ring[1][1], a2=ring[1][2];
    STAGE_A(a0,a1,a2, sp0,sp1,sp2,sp3,sp4,sp5, dq0,dq1,dq2,dq3,dq4,dq5);
  }
  LOADROW(0,4); LOADROW(1,5);

  // ---- main: k=0..94 covers rows 1..380 (body(i) consumes slot (i+1)&3) ----
  for (int k = 0; k < 95; ++k){
    const int i = 1 + 4*k;
    BODY(i,   2);
    BODY(i+1, 3);
    BODY(i+2, 0);
    BODY(i+3, 1);
  }
  // ---- tail: rows 381..383 ----
  BODY(381, 2);
  BODY(382, 3);
  BODY(383, 0);   // its Stage A output is junk (clamped row), never consumed

  if (lane == 63) partial[b] = r5;

#undef BODY
#undef STAGE_A
#undef STAGE_B
#undef LOADROW
}

// ---------------------------------------------------------------------------
// Kernel 3: mean of 128 partials -> out[0]
// ---------------------------------------------------------------------------
__global__ __launch_bounds__(64) void dtw_reduce(
    const float* __restrict__ partial, float* __restrict__ out)
{
  const int l = threadIdx.x;
  float v = partial[l] + partial[l + 64];
#pragma unroll
  for (int d = 32; d >= 1; d >>= 1) v += __shfl_xor(v, d, 64);
  if (l == 0) out[0] = v * (1.0f/128.0f);
}

extern "C" void kernel_launch(void* const* d_in, const int* in_sizes, int n_in,
                              void* d_out, int out_size, void* d_ws, size_t ws_size,
                              hipStream_t stream)
{
  (void)in_sizes; (void)n_in; (void)out_size; (void)ws_size;
  const float* s1 = (const float*)d_in[0];
  const float* s2 = (const float*)d_in[1];
  float* out = (float*)d_out;

  ushort* cost    = (ushort*)d_ws;                                   // 128*384*384*2 B
  float*  partial = (float*)((char*)d_ws + (size_t)128*147456*2);    // 128 floats

  dtw_cost_gemm<<<dim3(9, 128), dim3(256), 0, stream>>>(s1, s2, cost);
  dtw_dp<<<dim3(16), dim3(512), 0, stream>>>(cost, partial);
  dtw_reduce<<<dim3(1), dim3(64), 0, stream>>>(partial, out);
}